// Round 16
// baseline (265.813 us; speedup 1.0000x reference)
//
#include <hip/hip_runtime.h>

#define NUM_NODES 200000
#define DIM 128
#define BATCH 1024
#define K_NEG 5
#define CAP 16
#define NBLK 250          /* sim blocks; 200000 = 250 * 800 */
#define NT 25             /* 32-col tiles per block */
#define TCOL 32
#define THRESH 0.7f
#define FILL (-1.0e9f)

typedef __attribute__((ext_vector_type(8))) short short8;
typedef __attribute__((ext_vector_type(16))) float f32x16;

// round-to-nearest-even float -> bf16 bits (finite inputs only)
__device__ __forceinline__ unsigned short f2bf(float x) {
  unsigned u = __builtin_bit_cast(unsigned, x);
  return (unsigned short)((u + 0x7fffu + ((u >> 16) & 1u)) >> 16);
}

// ---------------- Threefry-2x32 (JAX-compatible) ----------------
__device__ __forceinline__ void tf2x32(unsigned k0, unsigned k1,
                                       unsigned x0, unsigned x1,
                                       unsigned* o0, unsigned* o1) {
  unsigned ks2 = k0 ^ k1 ^ 0x1BD11BDAu;
  unsigned v0 = x0 + k0, v1 = x1 + k1;
#define TFR(r) { v0 += v1; v1 = (v1 << r) | (v1 >> (32 - r)); v1 ^= v0; }
  TFR(13) TFR(15) TFR(26) TFR(6)   v0 += k1;  v1 += ks2 + 1u;
  TFR(17) TFR(29) TFR(16) TFR(24)  v0 += ks2; v1 += k0 + 2u;
  TFR(13) TFR(15) TFR(26) TFR(6)   v0 += k0;  v1 += k1 + 3u;
  TFR(17) TFR(29) TFR(16) TFR(24)  v0 += k1;  v1 += ks2 + 4u;
  TFR(13) TFR(15) TFR(26) TFR(6)   v0 += ks2; v1 += k0 + 5u;
#undef TFR
  *o0 = v0; *o1 = v1;
}

__device__ __forceinline__ unsigned rbits32(unsigned ka, unsigned kb, unsigned m) {
  unsigned o0, o1;
  tf2x32(ka, kb, 0u, m, &o0, &o1);
  return o0 ^ o1;
}

// ---- kernel 1: normalize src rows -> bf16 A-fragments (fragment-major), zero counters
// Fragment layout: chunk ((ms*8 + ks)*64 + lane64) is 8 bf16 (16 B) holding
// A[row = ms*32 + (lane64&31)][col = ks*16 + (lane64>>5)*8 + t], t=0..7.
__global__ void prep_kernel(const float* __restrict__ memory,
                            const int* __restrict__ src_nodes,
                            unsigned short* __restrict__ s16f,
                            int* __restrict__ cand_cnt) {
  int tid = threadIdx.x;
  int gid = blockIdx.x * 256 + tid;
  if (gid < BATCH) cand_cnt[gid] = 0;
  int row = blockIdx.x * 4 + (tid >> 6);   // 256 blocks x 4 waves = 1024 rows
  int L = tid & 63;                        // lane within the row's wave; cols 2L,2L+1
  int s = src_nodes[row];
  float2 v = ((const float2*)(memory + (size_t)s * DIM))[L];
  float ss = v.x * v.x + v.y * v.y;
#pragma unroll
  for (int off = 32; off > 0; off >>= 1) ss += __shfl_xor(ss, off);
  float inv = 1.0f / fmaxf(sqrtf(ss), 1e-12f);
  unsigned p = (unsigned)f2bf(v.x * inv) | ((unsigned)f2bf(v.y * inv) << 16);
  int ms = row >> 5, l32 = row & 31;
  int c = L >> 2;             // col chunk = col/8
  int ks = c >> 1, half = c & 1;
  ((unsigned*)s16f)[(((ms * 8 + ks) * 64) + half * 32 + l32) * 4 + (L & 3)] = p;
}

// ---- kernel 2: fully decoupled MFMA sim scan (no LDS, no barriers, no DMA) ----
// Rationale (R15 null result): co-resident blocks didn't help because the
// per-tile serial chain (stage -> MFMA -> vmcnt -> convert -> barrier-drain)
// is structural. This version removes ALL intra-block coupling: each wave
// holds its 4 A-subtiles in registers (read-once, 128 VGPR) and converts each
// 32-col B-tile FOR ITSELF (lane = own column, fused single-pass raw-bf16
// build, scale-after-MFMA). Conversion is 8x redundant (~+20 us VALU busy)
// but VALU and MFMA are separate pipes: wave-pairs on a SIMD overlap one
// wave's convert with the other's MFMA. The block's 8 waves touch the same
// 16 KB fp32 tile near-simultaneously -> L1/L2 hits keep HBM at read-once.
// After the A-load prologue each wave free-runs its 25-tile stream.
__global__ __launch_bounds__(512, 2) void sim_scan_kernel(
    const float* __restrict__ memory,
    const unsigned short* __restrict__ s16f,
    const int* __restrict__ dst_nodes,
    int* __restrict__ cand_cnt,
    float* __restrict__ cand_val,
    int* __restrict__ cand_idx) {
  int tid = threadIdx.x;
  int wid = tid >> 6;          // A-group: subtiles wid*4 .. wid*4+3
  int lane = tid & 63;
  int fh = lane >> 5;          // fragment half (cols ks*16 + fh*8 + 0..7)
  int l32 = lane & 31;
  int tb = blockIdx.x * NT;    // block's tile range [tb, tb+NT)

  // ---- prologue: load this wave's 4 A-subtiles into registers (once) ----
  const short8* __restrict__ af = (const short8*)s16f;
  short8 a[4][8];
#pragma unroll
  for (int m = 0; m < 4; ++m)
#pragma unroll
    for (int ks = 0; ks < 8; ++ks)
      a[m][ks] = af[(((wid * 4 + m) * 8) + ks) * 64 + lane];

  f32x16 Z;
#pragma unroll
  for (int i = 0; i < 16; ++i) Z[i] = 0.0f;

  // ---- main loop: 25 tiles, fully independent per wave ----
  for (int t = 0; t < NT; ++t) {
    int jb = (tb + t) * TCOL;
    int gj = jb + l32;                   // this lane's column

    // fused single-pass B build: RAW bf16 frags + sum-of-squares (R6 pattern)
    const float4* rp4 = (const float4*)(memory + (size_t)gj * DIM);
    short8 bf[8];
    float ss = 0.0f;
#pragma unroll
    for (int ks = 0; ks < 8; ++ks) {
      float4 qa = rp4[ks * 4 + fh * 2];
      float4 qb = rp4[ks * 4 + fh * 2 + 1];
      ss += qa.x * qa.x + qa.y * qa.y + qa.z * qa.z + qa.w * qa.w;
      ss += qb.x * qb.x + qb.y * qb.y + qb.z * qb.z + qb.w * qb.w;
      short8 f;
      f[0] = (short)f2bf(qa.x); f[1] = (short)f2bf(qa.y);
      f[2] = (short)f2bf(qa.z); f[3] = (short)f2bf(qa.w);
      f[4] = (short)f2bf(qb.x); f[5] = (short)f2bf(qb.y);
      f[6] = (short)f2bf(qb.z); f[7] = (short)f2bf(qb.w);
      bf[ks] = f;
    }
    ss += __shfl_xor(ss, 32);            // combine the two half-rows
    float nrm = fmaxf(sqrtf(ss), 1e-12f);
    float invv = 1.0f / nrm;
    float thr = THRESH * nrm;            // acc > 0.7*|b_j|  <=>  sim > 0.7

    // 32 MFMAs: 2 subtile-pairs x 8 ks, two independent acc chains each
#pragma unroll
    for (int mp = 0; mp < 2; ++mp) {
      f32x16 accA = __builtin_amdgcn_mfma_f32_32x32x16_bf16(a[mp * 2][0], bf[0], Z, 0, 0, 0);
      f32x16 accB = __builtin_amdgcn_mfma_f32_32x32x16_bf16(a[mp * 2 + 1][0], bf[0], Z, 0, 0, 0);
#pragma unroll
      for (int ks = 1; ks < 8; ++ks) {
        accA = __builtin_amdgcn_mfma_f32_32x32x16_bf16(a[mp * 2][ks], bf[ks], accA, 0, 0, 0);
        accB = __builtin_amdgcn_mfma_f32_32x32x16_bf16(a[mp * 2 + 1][ks], bf[ks], accB, 0, 0, 0);
      }
      float mA = accA[0], mB = accB[0];
#pragma unroll
      for (int i = 1; i < 16; ++i) { mA = fmaxf(mA, accA[i]); mB = fmaxf(mB, accB[i]); }
      if (mA > thr || mB > thr) {
        // C/D layout (m74/m101): col=lane&31, row=(r&3)+8*(r>>2)+4*(lane>>5)
#pragma unroll
        for (int e = 0; e < 2; ++e) {
#pragma unroll
          for (int r = 0; r < 16; ++r) {
            float raw = (e == 0) ? accA[r] : accB[r];
            if (raw > thr) {
              int gi = (wid * 4 + mp * 2 + e) * 32 + (r & 3) + 8 * (r >> 2) + 4 * fh;
              if (gj != dst_nodes[gi]) {
                int pq = atomicAdd(&cand_cnt[gi], 1);
                if (pq < CAP) {
                  cand_val[gi * CAP + pq] = raw * invv;
                  cand_idx[gi * CAP + pq] = gj;
                }
              }
            }
          }
        }
      }
    }
  }
}

// ---- kernel 3: top-5 per row, threefry negatives, assemble ----
__global__ void finalize_kernel(const int* __restrict__ src_nodes,
                                const int* __restrict__ dst_nodes,
                                const float* __restrict__ labels,
                                const float* __restrict__ ts,
                                const int* __restrict__ cand_cnt,
                                const float* __restrict__ cand_val,
                                const int* __restrict__ cand_idx,
                                float* __restrict__ out) {
  int r = blockIdx.x * 256 + threadIdx.x;
  if (r >= BATCH) return;
  const int TOT = BATCH + BATCH * K_NEG;  // 6144
  int srcv = src_nodes[r];
  float tsv = ts[r];
  out[r] = (float)srcv;
  out[TOT + r] = (float)dst_nodes[r];
  float l = labels[r];
  out[2 * TOT + r] = l * 0.9f + (1.0f - l) * 0.1f;
  out[3 * TOT + r] = tsv;

  int cnt = cand_cnt[r];
  cnt = cnt < CAP ? cnt : CAP;
  float cv[CAP]; int ci[CAP];
  for (int i = 0; i < cnt; ++i) { cv[i] = cand_val[r * CAP + i]; ci[i] = cand_idx[r * CAP + i]; }

  // jax.random.split(key(42)) — partitionable/foldlike: k_i = threefry(key, 0, i)
  unsigned k1a, k1b, k2a, k2b;
  tf2x32(0u, 42u, 0u, 0u, &k1a, &k1b);
  tf2x32(0u, 42u, 0u, 1u, &k2a, &k2b);

  const unsigned span = 200000u;
  const unsigned mult = 167296u;  // 2^32 % span

  for (int s = 0; s < K_NEG; ++s) {
    int sel = -1;
    for (int i = 0; i < cnt; ++i)
      if (sel < 0 || cv[i] > cv[sel] || (cv[i] == cv[sel] && ci[i] < ci[sel])) sel = i;
    float v = FILL; int idx = 0;
    if (sel >= 0) { v = cv[sel]; idx = ci[sel]; cv[sel] = FILL; ci[sel] = 0x7fffffff; }
    bool is_real = v > (FILL + 1.0f);

    unsigned m = (unsigned)(r * K_NEG + s);
    unsigned hi = rbits32(k1a, k1b, m);
    unsigned lo = rbits32(k2a, k2b, m);
    unsigned off = ((hi % span) * mult + (lo % span)) % span;  // uint32 wrap, as JAX
    int rd = (int)off;
    if (rd == srcv) rd = (rd + 1) % NUM_NODES;
    int fd = is_real ? idx : rd;

    int mi = (int)m;
    out[BATCH + mi] = (float)srcv;
    out[TOT + BATCH + mi] = (float)fd;
    out[2 * TOT + BATCH + mi] = 0.1f;   // smoothing of label 0
    out[3 * TOT + BATCH + mi] = tsv;
    out[4 * TOT + mi] = v;
  }
}

extern "C" void kernel_launch(void* const* d_in, const int* in_sizes, int n_in,
                              void* d_out, int out_size, void* d_ws, size_t ws_size,
                              hipStream_t stream) {
  const int* src = (const int*)d_in[0];
  const int* dst = (const int*)d_in[1];
  const float* labels = (const float*)d_in[2];
  const float* ts = (const float*)d_in[3];
  const float* memory = (const float*)d_in[4];
  float* out = (float*)d_out;

  char* ws = (char*)d_ws;
  unsigned short* s16f = (unsigned short*)ws;       // 1024*128*2 = 262144 B (fragment-major)
  int* cand_cnt = (int*)(ws + 262144);              // 4096 B
  float* cand_val = (float*)(ws + 266240);          // 65536 B
  int* cand_idx = (int*)(ws + 331776);              // 65536 B

  prep_kernel<<<256, 256, 0, stream>>>(memory, src, s16f, cand_cnt);
  sim_scan_kernel<<<NBLK, 512, 0, stream>>>(memory, s16f, dst, cand_cnt, cand_val, cand_idx);
  finalize_kernel<<<(BATCH + 255) / 256, 256, 0, stream>>>(src, dst, labels, ts,
                                                           cand_cnt, cand_val, cand_idx, out);
}

// Round 17
// 222.197 us; speedup vs baseline: 1.1963x; 1.1963x over previous
//
#include <hip/hip_runtime.h>

#define NUM_NODES 200000
#define DIM 128
#define BATCH 1024
#define K_NEG 5
#define CAP 16
#define NBLK 250          /* sim blocks; 200000 = 250 * 800 */
#define NTPB 25           /* 32-col tiles per block */
#define TCOL 32
#define THRESH 0.7f
#define FILL (-1.0e9f)

typedef __attribute__((ext_vector_type(8))) short short8;
typedef __attribute__((ext_vector_type(16))) float f32x16;

// round-to-nearest-even float -> bf16 bits (finite inputs only)
__device__ __forceinline__ unsigned short f2bf(float x) {
  unsigned u = __builtin_bit_cast(unsigned, x);
  return (unsigned short)((u + 0x7fffu + ((u >> 16) & 1u)) >> 16);
}

// async global->LDS: 16 bytes per lane; lane i lands at ldsbase + i*16
__device__ __forceinline__ void stage16(const void* g, void* l) {
  __builtin_amdgcn_global_load_lds(
      (const __attribute__((address_space(1))) unsigned int*)g,
      (__attribute__((address_space(3))) unsigned int*)l,
      16, 0, 0);
}

// ---------------- Threefry-2x32 (JAX-compatible) ----------------
__device__ __forceinline__ void tf2x32(unsigned k0, unsigned k1,
                                       unsigned x0, unsigned x1,
                                       unsigned* o0, unsigned* o1) {
  unsigned ks2 = k0 ^ k1 ^ 0x1BD11BDAu;
  unsigned v0 = x0 + k0, v1 = x1 + k1;
#define TFR(r) { v0 += v1; v1 = (v1 << r) | (v1 >> (32 - r)); v1 ^= v0; }
  TFR(13) TFR(15) TFR(26) TFR(6)   v0 += k1;  v1 += ks2 + 1u;
  TFR(17) TFR(29) TFR(16) TFR(24)  v0 += ks2; v1 += k0 + 2u;
  TFR(13) TFR(15) TFR(26) TFR(6)   v0 += k0;  v1 += k1 + 3u;
  TFR(17) TFR(29) TFR(16) TFR(24)  v0 += k1;  v1 += ks2 + 4u;
  TFR(13) TFR(15) TFR(26) TFR(6)   v0 += ks2; v1 += k0 + 5u;
#undef TFR
  *o0 = v0; *o1 = v1;
}

__device__ __forceinline__ unsigned rbits32(unsigned ka, unsigned kb, unsigned m) {
  unsigned o0, o1;
  tf2x32(ka, kb, 0u, m, &o0, &o1);
  return o0 ^ o1;
}

// ---- kernel 1: normalize src rows -> bf16 A-fragments (fragment-major), zero counters
// Fragment layout: chunk ((ms*8 + ks)*64 + lane64) is 8 bf16 (16 B) holding
// A[row = ms*32 + (lane64&31)][col = ks*16 + (lane64>>5)*8 + t], t=0..7.
__global__ void prep_kernel(const float* __restrict__ memory,
                            const int* __restrict__ src_nodes,
                            unsigned short* __restrict__ s16f,
                            int* __restrict__ cand_cnt) {
  int tid = threadIdx.x;
  int gid = blockIdx.x * 256 + tid;
  if (gid < BATCH) cand_cnt[gid] = 0;
  int row = blockIdx.x * 4 + (tid >> 6);   // 256 blocks x 4 waves = 1024 rows
  int L = tid & 63;                        // lane within the row's wave; cols 2L,2L+1
  int s = src_nodes[row];
  float2 v = ((const float2*)(memory + (size_t)s * DIM))[L];
  float ss = v.x * v.x + v.y * v.y;
#pragma unroll
  for (int off = 32; off > 0; off >>= 1) ss += __shfl_xor(ss, off);
  float inv = 1.0f / fmaxf(sqrtf(ss), 1e-12f);
  unsigned p = (unsigned)f2bf(v.x * inv) | ((unsigned)f2bf(v.y * inv) << 16);
  int ms = row >> 5, l32 = row & 31;
  int c = L >> 2;             // col chunk = col/8
  int ks = c >> 1, half = c & 1;
  ((unsigned*)s16f)[(((ms * 8 + ks) * 64) + half * 32 + l32) * 4 + (L & 3)] = p;
}

// ---- kernel 2: read-once MFMA sim scan, 4-tile barrier periods ----
// Same verified R13 dataflow (per-wave global_load_lds staging of own 4 cols,
// one vmcnt(0)+convert into shared XOR-swizzled frag LDS, scale-after-MFMA),
// but the barrier period covers FOUR 32-col tiles: per period each wave issues
// 8 DMAs, runs 128 MFMAs (4 slabs), one vmcnt(0), converts 4 tiles, one
// barrier. The measured per-tile serial overhead (~4200 cyc: DMA issue +
// vmcnt + convert + barrier drain/skew) is amortized 4x against ~4130 cyc of
// MFMA issue -> MfmaUtil should roughly double. Barriers: 25 -> 7.
// Tiles 0..23 in 6 periods of 4; tile 24 staged during period 5 and run as a
// barrier-free epilogue. LDS 132 KB (1 block/CU, as measured regime).
__global__ __launch_bounds__(512, 2) void sim_scan_kernel(
    const float* __restrict__ memory,
    const unsigned short* __restrict__ s16f,
    const int* __restrict__ dst_nodes,
    int* __restrict__ cand_cnt,
    float* __restrict__ cand_val,
    int* __restrict__ cand_idx) {
  __shared__ char qbuf[8][8192];              // per-wave staged raw cols (4 tiles x 2 KB)
  __shared__ unsigned short fragb[2][16384];  // bf16 frags, 4 tile-slabs x 8 KB per parity
  __shared__ float nrmb[2][128];              // per-column L2 norms (4 tiles x 32)

  int tid = threadIdx.x;
  int wid = tid >> 6;
  int lane = tid & 63;
  int half = lane >> 5;
  int l32 = lane & 31;
  int gtb = blockIdx.x * NTPB;       // block's global tile base

  int ccol = wid * 4 + (lane & 3);   // this lane's owned column (0..31 in tile)
  int cseg = lane >> 2;              // element group [cseg*8, cseg*8+8)

  const char* mb = (const char*)memory;
  char* qb = &qbuf[wid][0];

  // stage local tile `lt` into qbuf slot `tt` (own 4 columns, 2 DMAs)
#define QSTAGE1(lt, tt) {                                                       \
    const char* g = mb + (size_t)((gtb + (lt)) * TCOL + ccol) * 512 + (cseg << 5); \
    stage16(g, qb + (tt) * 2048);                                               \
    stage16(g + 16, qb + (tt) * 2048 + 1024);                                   \
  }

  // convert qbuf slot tt -> frag[p2] slab tt (+ norms); own column only
#define QCONV1(p2, tt) {                                                        \
    float4 q0 = *(const float4*)(qb + (tt) * 2048 + (lane << 4));               \
    float4 q1 = *(const float4*)(qb + (tt) * 2048 + 1024 + (lane << 4));        \
    float ss = q0.x * q0.x + q0.y * q0.y + q0.z * q0.z + q0.w * q0.w            \
             + q1.x * q1.x + q1.y * q1.y + q1.z * q1.z + q1.w * q1.w;           \
    ss += __shfl_xor(ss, 4); ss += __shfl_xor(ss, 8);                           \
    ss += __shfl_xor(ss, 16); ss += __shfl_xor(ss, 32);                         \
    short8 f;                                                                   \
    f[0] = (short)f2bf(q0.x); f[1] = (short)f2bf(q0.y);                         \
    f[2] = (short)f2bf(q0.z); f[3] = (short)f2bf(q0.w);                         \
    f[4] = (short)f2bf(q1.x); f[5] = (short)f2bf(q1.y);                         \
    f[6] = (short)f2bf(q1.z); f[7] = (short)f2bf(q1.w);                         \
    *(short8*)((char*)fragb[p2] + (tt) * 8192 +                                 \
               ((cseg * 32 + (ccol ^ (cseg & 7))) << 4)) = f;                   \
    if (cseg == 0) nrmb[p2][(tt) * 32 + ccol] = fmaxf(sqrtf(ss), 1e-12f);       \
  }

  // MFMA one tile: frag[par] slab tt, global local-tile lt
#define MFMA1(par, tt, lt) {                                                    \
    float nv = nrmb[par][(tt) * 32 + l32];                                      \
    float thr = THRESH * nv;                                                    \
    float invv = 1.0f / nv;                                                     \
    int gj = (gtb + (lt)) * TCOL + l32;                                         \
    short8 bf[8];                                                               \
    _Pragma("unroll")                                                           \
    for (int ks = 0; ks < 8; ++ks) {                                            \
      int s0 = 2 * ks + half;                                                   \
      bf[ks] = *(const short8*)((char*)fragb[par] + (tt) * 8192 +               \
                                ((s0 * 32 + (l32 ^ (s0 & 7))) << 4));           \
    }                                                                           \
    _Pragma("unroll")                                                           \
    for (int mp = 0; mp < 2; ++mp) {                                            \
      f32x16 accA = __builtin_amdgcn_mfma_f32_32x32x16_bf16(a[mp*2][0], bf[0], Z, 0, 0, 0); \
      f32x16 accB = __builtin_amdgcn_mfma_f32_32x32x16_bf16(a[mp*2+1][0], bf[0], Z, 0, 0, 0); \
      _Pragma("unroll")                                                         \
      for (int ks = 1; ks < 8; ++ks) {                                          \
        accA = __builtin_amdgcn_mfma_f32_32x32x16_bf16(a[mp*2][ks], bf[ks], accA, 0, 0, 0); \
        accB = __builtin_amdgcn_mfma_f32_32x32x16_bf16(a[mp*2+1][ks], bf[ks], accB, 0, 0, 0); \
      }                                                                         \
      float mA = accA[0], mB = accB[0];                                         \
      _Pragma("unroll")                                                         \
      for (int i2 = 1; i2 < 16; ++i2) { mA = fmaxf(mA, accA[i2]); mB = fmaxf(mB, accB[i2]); } \
      if (mA > thr || mB > thr) {                                               \
        _Pragma("unroll")                                                       \
        for (int e = 0; e < 2; ++e) {                                           \
          _Pragma("unroll")                                                     \
          for (int r = 0; r < 16; ++r) {                                        \
            float raw = (e == 0) ? accA[r] : accB[r];                           \
            if (raw > thr) {                                                    \
              int gi = (wid * 4 + mp * 2 + e) * 32 + (r & 3) + 8 * (r >> 2) + 4 * half; \
              if (gj != dst_nodes[gi]) {                                        \
                int pq = atomicAdd(&cand_cnt[gi], 1);                           \
                if (pq < CAP) {                                                 \
                  cand_val[gi * CAP + pq] = raw * invv;                         \
                  cand_idx[gi * CAP + pq] = gj;                                 \
                }                                                               \
              }                                                                 \
            }                                                                   \
          }                                                                     \
        }                                                                       \
      }                                                                         \
    }                                                                           \
  }

  // ---- prologue: stage period 0 (tiles 0-3), A-load, convert, barrier ----
#pragma unroll
  for (int tt = 0; tt < 4; ++tt) QSTAGE1(tt, tt);
  const short8* __restrict__ af = (const short8*)s16f;
  short8 a[4][8];
#pragma unroll
  for (int m = 0; m < 4; ++m)
#pragma unroll
    for (int ks = 0; ks < 8; ++ks)
      a[m][ks] = af[(((wid * 4 + m) * 8) + ks) * 64 + lane];
  asm volatile("s_waitcnt vmcnt(0)" ::: "memory");
  __builtin_amdgcn_sched_barrier(0);
#pragma unroll
  for (int tt = 0; tt < 4; ++tt) QCONV1(0, tt);
  __syncthreads();          // frag[0] (tiles 0-3) visible

  f32x16 Z;
#pragma unroll
  for (int i = 0; i < 16; ++i) Z[i] = 0.0f;

  // ---- main loop: 6 periods of 4 tiles, one barrier each ----
  for (int p = 0; p < 6; ++p) {
    int par = p & 1;
    int base = p * 4;

    // stage next period's tiles (p<5: 4 tiles; p==5: the single tile 24)
    if (p < 5) {
#pragma unroll
      for (int tt = 0; tt < 4; ++tt) QSTAGE1(base + 4 + tt, tt);
    } else {
      QSTAGE1(24, 0);
    }

    // MFMA the current period's 4 tiles
    for (int tt = 0; tt < 4; ++tt) MFMA1(par, tt, base + tt);

    // own-wave wait + convert next period into frag[par^1]
    asm volatile("s_waitcnt vmcnt(0)" ::: "memory");
    __builtin_amdgcn_sched_barrier(0);
    if (p < 5) {
#pragma unroll
      for (int tt = 0; tt < 4; ++tt) QCONV1(par ^ 1, tt);
    } else {
      QCONV1(par ^ 1, 0);
    }
    __syncthreads();
  }

  // ---- epilogue: tile 24 (frag[0], slab 0), no barrier ----
  MFMA1(0, 0, 24);
#undef QSTAGE1
#undef QCONV1
#undef MFMA1
}

// ---- kernel 3: top-5 per row, threefry negatives, assemble ----
__global__ void finalize_kernel(const int* __restrict__ src_nodes,
                                const int* __restrict__ dst_nodes,
                                const float* __restrict__ labels,
                                const float* __restrict__ ts,
                                const int* __restrict__ cand_cnt,
                                const float* __restrict__ cand_val,
                                const int* __restrict__ cand_idx,
                                float* __restrict__ out) {
  int r = blockIdx.x * 256 + threadIdx.x;
  if (r >= BATCH) return;
  const int TOT = BATCH + BATCH * K_NEG;  // 6144
  int srcv = src_nodes[r];
  float tsv = ts[r];
  out[r] = (float)srcv;
  out[TOT + r] = (float)dst_nodes[r];
  float l = labels[r];
  out[2 * TOT + r] = l * 0.9f + (1.0f - l) * 0.1f;
  out[3 * TOT + r] = tsv;

  int cnt = cand_cnt[r];
  cnt = cnt < CAP ? cnt : CAP;
  float cv[CAP]; int ci[CAP];
  for (int i = 0; i < cnt; ++i) { cv[i] = cand_val[r * CAP + i]; ci[i] = cand_idx[r * CAP + i]; }

  // jax.random.split(key(42)) — partitionable/foldlike: k_i = threefry(key, 0, i)
  unsigned k1a, k1b, k2a, k2b;
  tf2x32(0u, 42u, 0u, 0u, &k1a, &k1b);
  tf2x32(0u, 42u, 0u, 1u, &k2a, &k2b);

  const unsigned span = 200000u;
  const unsigned mult = 167296u;  // 2^32 % span

  for (int s = 0; s < K_NEG; ++s) {
    int sel = -1;
    for (int i = 0; i < cnt; ++i)
      if (sel < 0 || cv[i] > cv[sel] || (cv[i] == cv[sel] && ci[i] < ci[sel])) sel = i;
    float v = FILL; int idx = 0;
    if (sel >= 0) { v = cv[sel]; idx = ci[sel]; cv[sel] = FILL; ci[sel] = 0x7fffffff; }
    bool is_real = v > (FILL + 1.0f);

    unsigned m = (unsigned)(r * K_NEG + s);
    unsigned hi = rbits32(k1a, k1b, m);
    unsigned lo = rbits32(k2a, k2b, m);
    unsigned off = ((hi % span) * mult + (lo % span)) % span;  // uint32 wrap, as JAX
    int rd = (int)off;
    if (rd == srcv) rd = (rd + 1) % NUM_NODES;
    int fd = is_real ? idx : rd;

    int mi = (int)m;
    out[BATCH + mi] = (float)srcv;
    out[TOT + BATCH + mi] = (float)fd;
    out[2 * TOT + BATCH + mi] = 0.1f;   // smoothing of label 0
    out[3 * TOT + BATCH + mi] = tsv;
    out[4 * TOT + mi] = v;
  }
}

extern "C" void kernel_launch(void* const* d_in, const int* in_sizes, int n_in,
                              void* d_out, int out_size, void* d_ws, size_t ws_size,
                              hipStream_t stream) {
  const int* src = (const int*)d_in[0];
  const int* dst = (const int*)d_in[1];
  const float* labels = (const float*)d_in[2];
  const float* ts = (const float*)d_in[3];
  const float* memory = (const float*)d_in[4];
  float* out = (float*)d_out;

  char* ws = (char*)d_ws;
  unsigned short* s16f = (unsigned short*)ws;       // 1024*128*2 = 262144 B (fragment-major)
  int* cand_cnt = (int*)(ws + 262144);              // 4096 B
  float* cand_val = (float*)(ws + 266240);          // 65536 B
  int* cand_idx = (int*)(ws + 331776);              // 65536 B

  prep_kernel<<<256, 256, 0, stream>>>(memory, src, s16f, cand_cnt);
  sim_scan_kernel<<<NBLK, 512, 0, stream>>>(memory, s16f, dst, cand_cnt, cand_val, cand_idx);
  finalize_kernel<<<(BATCH + 255) / 256, 256, 0, stream>>>(src, dst, labels, ts,
                                                           cand_cnt, cand_val, cand_idx, out);
}

// Round 18
// 189.103 us; speedup vs baseline: 1.4056x; 1.1750x over previous
//
#include <hip/hip_runtime.h>

#define NUM_NODES 200000
#define DIM 128
#define BATCH 1024
#define K_NEG 5
#define CAP 16
#define NBLK 250          /* sim blocks; 200000 = 250 * 800 */
#define NTPB 25           /* 32-col tiles per block */
#define TCOL 32
#define THRESH 0.7f
#define FILL (-1.0e9f)

typedef __attribute__((ext_vector_type(8))) short short8;
typedef __attribute__((ext_vector_type(16))) float f32x16;

// round-to-nearest-even float -> bf16 bits (finite inputs only)
__device__ __forceinline__ unsigned short f2bf(float x) {
  unsigned u = __builtin_bit_cast(unsigned, x);
  return (unsigned short)((u + 0x7fffu + ((u >> 16) & 1u)) >> 16);
}

// async global->LDS: 16 bytes per lane; lane i lands at ldsbase + i*16
__device__ __forceinline__ void stage16(const void* g, void* l) {
  __builtin_amdgcn_global_load_lds(
      (const __attribute__((address_space(1))) unsigned int*)g,
      (__attribute__((address_space(3))) unsigned int*)l,
      16, 0, 0);
}

// ---------------- Threefry-2x32 (JAX-compatible) ----------------
__device__ __forceinline__ void tf2x32(unsigned k0, unsigned k1,
                                       unsigned x0, unsigned x1,
                                       unsigned* o0, unsigned* o1) {
  unsigned ks2 = k0 ^ k1 ^ 0x1BD11BDAu;
  unsigned v0 = x0 + k0, v1 = x1 + k1;
#define TFR(r) { v0 += v1; v1 = (v1 << r) | (v1 >> (32 - r)); v1 ^= v0; }
  TFR(13) TFR(15) TFR(26) TFR(6)   v0 += k1;  v1 += ks2 + 1u;
  TFR(17) TFR(29) TFR(16) TFR(24)  v0 += ks2; v1 += k0 + 2u;
  TFR(13) TFR(15) TFR(26) TFR(6)   v0 += k0;  v1 += k1 + 3u;
  TFR(17) TFR(29) TFR(16) TFR(24)  v0 += k1;  v1 += ks2 + 4u;
  TFR(13) TFR(15) TFR(26) TFR(6)   v0 += ks2; v1 += k0 + 5u;
#undef TFR
  *o0 = v0; *o1 = v1;
}

__device__ __forceinline__ unsigned rbits32(unsigned ka, unsigned kb, unsigned m) {
  unsigned o0, o1;
  tf2x32(ka, kb, 0u, m, &o0, &o1);
  return o0 ^ o1;
}

// ---- kernel 1: normalize src rows -> bf16 A-fragments (fragment-major), zero counters
// Fragment layout: chunk ((ms*8 + ks)*64 + lane64) is 8 bf16 (16 B) holding
// A[row = ms*32 + (lane64&31)][col = ks*16 + (lane64>>5)*8 + t], t=0..7.
__global__ void prep_kernel(const float* __restrict__ memory,
                            const int* __restrict__ src_nodes,
                            unsigned short* __restrict__ s16f,
                            int* __restrict__ cand_cnt) {
  int tid = threadIdx.x;
  int gid = blockIdx.x * 256 + tid;
  if (gid < BATCH) cand_cnt[gid] = 0;
  int row = blockIdx.x * 4 + (tid >> 6);   // 256 blocks x 4 waves = 1024 rows
  int L = tid & 63;                        // lane within the row's wave; cols 2L,2L+1
  int s = src_nodes[row];
  float2 v = ((const float2*)(memory + (size_t)s * DIM))[L];
  float ss = v.x * v.x + v.y * v.y;
#pragma unroll
  for (int off = 32; off > 0; off >>= 1) ss += __shfl_xor(ss, off);
  float inv = 1.0f / fmaxf(sqrtf(ss), 1e-12f);
  unsigned p = (unsigned)f2bf(v.x * inv) | ((unsigned)f2bf(v.y * inv) << 16);
  int ms = row >> 5, l32 = row & 31;
  int c = L >> 2;             // col chunk = col/8
  int ks = c >> 1, half = c & 1;
  ((unsigned*)s16f)[(((ms * 8 + ks) * 64) + half * 32 + l32) * 4 + (L & 3)] = p;
}

// ---- kernel 2: read-once MFMA sim scan, 2-tile barrier periods ----
// Exact R13 dataflow (the verified 65 us structure: per-wave global_load_lds
// staging of own 4 cols, own-wave vmcnt(0), convert-once into XOR-swizzled
// frag LDS, scale-after-MFMA), with the barrier period widened to TWO tiles:
// stage 2 tiles -> 2 MFMA phases -> vmcnt(0) -> convert 2 tiles -> barrier.
// Barriers 26 -> 13; per-period serial overhead (drain + skew) amortized 2x.
// All slab indices compile-time constant; one bf[8]+acc-pair live at a time
// (the proven 128-VGPR shape — R17's 4-slab variant spilled, this must not).
__global__ __launch_bounds__(512, 2) void sim_scan_kernel(
    const float* __restrict__ memory,
    const unsigned short* __restrict__ s16f,
    const int* __restrict__ dst_nodes,
    int* __restrict__ cand_cnt,
    float* __restrict__ cand_val,
    int* __restrict__ cand_idx) {
  __shared__ char qbuf[8][4096];             // per-wave staged raw cols (2 slots x 2 KB)
  __shared__ unsigned short fragb[2][8192];  // 2 par x 2 slabs x 8 KB bf16 frags
  __shared__ float nrmb[2][2][32];           // per-column L2 norms [par][slab][col]

  int tid = threadIdx.x;
  int wid = tid >> 6;
  int lane = tid & 63;
  int half = lane >> 5;
  int l32 = lane & 31;
  int gtb = blockIdx.x * NTPB;       // block's global tile base

  int ccol = wid * 4 + (lane & 3);   // this lane's owned column (0..31 in tile)
  int cseg = lane >> 2;              // element group [cseg*8, cseg*8+8)

  const char* mb = (const char*)memory;
  char* qb = &qbuf[wid][0];

  // stage tile (gtb+lt)'s own-4-columns into qbuf slot `slot` (2 DMAs)
#define QSTAGE(lt, slot) {                                                      \
    const char* g = mb + (size_t)((gtb + (lt)) * TCOL + ccol) * 512 + (cseg << 5); \
    stage16(g, qb + (slot) * 2048);                                             \
    stage16(g + 16, qb + (slot) * 2048 + 1024);                                 \
  }

  // read back own 32 B from qbuf slot, convert -> fragb[p] slab + norms
#define QCONV(p, slot) {                                                        \
    float4 q0 = *(const float4*)(qb + (slot) * 2048 + (lane << 4));             \
    float4 q1 = *(const float4*)(qb + (slot) * 2048 + 1024 + (lane << 4));      \
    float ss = q0.x * q0.x + q0.y * q0.y + q0.z * q0.z + q0.w * q0.w            \
             + q1.x * q1.x + q1.y * q1.y + q1.z * q1.z + q1.w * q1.w;           \
    ss += __shfl_xor(ss, 4); ss += __shfl_xor(ss, 8);                           \
    ss += __shfl_xor(ss, 16); ss += __shfl_xor(ss, 32);                         \
    short8 f;                                                                   \
    f[0] = (short)f2bf(q0.x); f[1] = (short)f2bf(q0.y);                         \
    f[2] = (short)f2bf(q0.z); f[3] = (short)f2bf(q0.w);                         \
    f[4] = (short)f2bf(q1.x); f[5] = (short)f2bf(q1.y);                         \
    f[6] = (short)f2bf(q1.z); f[7] = (short)f2bf(q1.w);                         \
    *(short8*)((char*)fragb[p] + (slot) * 8192 +                                \
               ((cseg * 32 + (ccol ^ (cseg & 7))) << 4)) = f;                   \
    if (cseg == 0) nrmb[p][slot][ccol] = fmaxf(sqrtf(ss), 1e-12f);              \
  }

  // MFMA one tile from fragb[p] slab `slot`, local tile lt (R13 phase body)
#define MFMA_T(p, slot, lt) {                                                   \
    float nv = nrmb[p][slot][l32];                                              \
    float thr = THRESH * nv;                                                    \
    float invv = 1.0f / nv;                                                     \
    int gj = (gtb + (lt)) * TCOL + l32;                                         \
    short8 bf[8];                                                               \
    _Pragma("unroll")                                                           \
    for (int ks = 0; ks < 8; ++ks) {                                            \
      int s0 = 2 * ks + half;                                                   \
      bf[ks] = *(const short8*)((char*)fragb[p] + (slot) * 8192 +               \
                                ((s0 * 32 + (l32 ^ (s0 & 7))) << 4));           \
    }                                                                           \
    _Pragma("unroll")                                                           \
    for (int mp = 0; mp < 2; ++mp) {                                            \
      f32x16 accA = __builtin_amdgcn_mfma_f32_32x32x16_bf16(a[mp*2][0], bf[0], Z, 0, 0, 0); \
      f32x16 accB = __builtin_amdgcn_mfma_f32_32x32x16_bf16(a[mp*2+1][0], bf[0], Z, 0, 0, 0); \
      _Pragma("unroll")                                                         \
      for (int ks = 1; ks < 8; ++ks) {                                          \
        accA = __builtin_amdgcn_mfma_f32_32x32x16_bf16(a[mp*2][ks], bf[ks], accA, 0, 0, 0); \
        accB = __builtin_amdgcn_mfma_f32_32x32x16_bf16(a[mp*2+1][ks], bf[ks], accB, 0, 0, 0); \
      }                                                                         \
      float mA = accA[0], mB = accB[0];                                         \
      _Pragma("unroll")                                                         \
      for (int i2 = 1; i2 < 16; ++i2) { mA = fmaxf(mA, accA[i2]); mB = fmaxf(mB, accB[i2]); } \
      if (mA > thr || mB > thr) {                                               \
        _Pragma("unroll")                                                       \
        for (int e = 0; e < 2; ++e) {                                           \
          _Pragma("unroll")                                                     \
          for (int r = 0; r < 16; ++r) {                                        \
            float raw = (e == 0) ? accA[r] : accB[r];                           \
            if (raw > thr) {                                                    \
              int gi = (wid * 4 + mp * 2 + e) * 32 + (r & 3) + 8 * (r >> 2) + 4 * half; \
              if (gj != dst_nodes[gi]) {                                        \
                int pq = atomicAdd(&cand_cnt[gi], 1);                           \
                if (pq < CAP) {                                                 \
                  cand_val[gi * CAP + pq] = raw * invv;                         \
                  cand_idx[gi * CAP + pq] = gj;                                 \
                }                                                               \
              }                                                                 \
            }                                                                   \
          }                                                                     \
        }                                                                       \
      }                                                                         \
    }                                                                           \
  }

  // ---- prologue: stage tiles 0,1; A-load; convert into par 0; barrier ----
  QSTAGE(0, 0);
  QSTAGE(1, 1);
  const short8* __restrict__ af = (const short8*)s16f;
  short8 a[4][8];
#pragma unroll
  for (int m = 0; m < 4; ++m)
#pragma unroll
    for (int ks = 0; ks < 8; ++ks)
      a[m][ks] = af[(((wid * 4 + m) * 8) + ks) * 64 + lane];
  asm volatile("s_waitcnt vmcnt(0)" ::: "memory");
  __builtin_amdgcn_sched_barrier(0);
  QCONV(0, 0);
  QCONV(0, 1);
  __syncthreads();          // fragb[0] (tiles 0,1) visible

  f32x16 Z;
#pragma unroll
  for (int i = 0; i < 16; ++i) Z[i] = 0.0f;

  // ---- main loop: 12 periods of 2 tiles, one barrier each ----
  for (int p = 0; p < 12; ++p) {
    int par = p & 1;
    int b0 = p * 2;

    // stage next period's tiles (p<11: 2 tiles; p==11: the single tile 24)
    if (p < 11) {
      QSTAGE(b0 + 2, 0);
      QSTAGE(b0 + 3, 1);
    } else {
      QSTAGE(24, 0);
    }

    // MFMA the current period's 2 tiles (static slab indices)
    MFMA_T(par, 0, b0);
    MFMA_T(par, 1, b0 + 1);

    // own-wave wait + convert next period into fragb[par^1]
    asm volatile("s_waitcnt vmcnt(0)" ::: "memory");
    __builtin_amdgcn_sched_barrier(0);
    if (p < 11) {
      QCONV(par ^ 1, 0);
      QCONV(par ^ 1, 1);
    } else {
      QCONV(par ^ 1, 0);
    }
    __syncthreads();
  }

  // ---- epilogue: tile 24 (fragb[0], slab 0), no barrier ----
  MFMA_T(0, 0, 24);
#undef QSTAGE
#undef QCONV
#undef MFMA_T
}

// ---- kernel 3: top-5 per row, threefry negatives, assemble ----
__global__ void finalize_kernel(const int* __restrict__ src_nodes,
                                const int* __restrict__ dst_nodes,
                                const float* __restrict__ labels,
                                const float* __restrict__ ts,
                                const int* __restrict__ cand_cnt,
                                const float* __restrict__ cand_val,
                                const int* __restrict__ cand_idx,
                                float* __restrict__ out) {
  int r = blockIdx.x * 256 + threadIdx.x;
  if (r >= BATCH) return;
  const int TOT = BATCH + BATCH * K_NEG;  // 6144
  int srcv = src_nodes[r];
  float tsv = ts[r];
  out[r] = (float)srcv;
  out[TOT + r] = (float)dst_nodes[r];
  float l = labels[r];
  out[2 * TOT + r] = l * 0.9f + (1.0f - l) * 0.1f;
  out[3 * TOT + r] = tsv;

  int cnt = cand_cnt[r];
  cnt = cnt < CAP ? cnt : CAP;
  float cv[CAP]; int ci[CAP];
  for (int i = 0; i < cnt; ++i) { cv[i] = cand_val[r * CAP + i]; ci[i] = cand_idx[r * CAP + i]; }

  // jax.random.split(key(42)) — partitionable/foldlike: k_i = threefry(key, 0, i)
  unsigned k1a, k1b, k2a, k2b;
  tf2x32(0u, 42u, 0u, 0u, &k1a, &k1b);
  tf2x32(0u, 42u, 0u, 1u, &k2a, &k2b);

  const unsigned span = 200000u;
  const unsigned mult = 167296u;  // 2^32 % span

  for (int s = 0; s < K_NEG; ++s) {
    int sel = -1;
    for (int i = 0; i < cnt; ++i)
      if (sel < 0 || cv[i] > cv[sel] || (cv[i] == cv[sel] && ci[i] < ci[sel])) sel = i;
    float v = FILL; int idx = 0;
    if (sel >= 0) { v = cv[sel]; idx = ci[sel]; cv[sel] = FILL; ci[sel] = 0x7fffffff; }
    bool is_real = v > (FILL + 1.0f);

    unsigned m = (unsigned)(r * K_NEG + s);
    unsigned hi = rbits32(k1a, k1b, m);
    unsigned lo = rbits32(k2a, k2b, m);
    unsigned off = ((hi % span) * mult + (lo % span)) % span;  // uint32 wrap, as JAX
    int rd = (int)off;
    if (rd == srcv) rd = (rd + 1) % NUM_NODES;
    int fd = is_real ? idx : rd;

    int mi = (int)m;
    out[BATCH + mi] = (float)srcv;
    out[TOT + BATCH + mi] = (float)fd;
    out[2 * TOT + BATCH + mi] = 0.1f;   // smoothing of label 0
    out[3 * TOT + BATCH + mi] = tsv;
    out[4 * TOT + mi] = v;
  }
}

extern "C" void kernel_launch(void* const* d_in, const int* in_sizes, int n_in,
                              void* d_out, int out_size, void* d_ws, size_t ws_size,
                              hipStream_t stream) {
  const int* src = (const int*)d_in[0];
  const int* dst = (const int*)d_in[1];
  const float* labels = (const float*)d_in[2];
  const float* ts = (const float*)d_in[3];
  const float* memory = (const float*)d_in[4];
  float* out = (float*)d_out;

  char* ws = (char*)d_ws;
  unsigned short* s16f = (unsigned short*)ws;       // 1024*128*2 = 262144 B (fragment-major)
  int* cand_cnt = (int*)(ws + 262144);              // 4096 B
  float* cand_val = (float*)(ws + 266240);          // 65536 B
  int* cand_idx = (int*)(ws + 331776);              // 65536 B

  prep_kernel<<<256, 256, 0, stream>>>(memory, src, s16f, cand_cnt);
  sim_scan_kernel<<<NBLK, 512, 0, stream>>>(memory, s16f, dst, cand_cnt, cand_val, cand_idx);
  finalize_kernel<<<(BATCH + 255) / 256, 256, 0, stream>>>(src, dst, labels, ts,
                                                           cand_cnt, cand_val, cand_idx, out);
}

// Round 19
// 187.725 us; speedup vs baseline: 1.4160x; 1.0073x over previous
//
#include <hip/hip_runtime.h>

#define NUM_NODES 200000
#define DIM 128
#define BATCH 1024
#define K_NEG 5
#define CAP 16
#define NBLK 250          /* sim blocks; 200000 = 250 * 800 */
#define CPB 800           /* columns per block */
#define TCOL 32           /* columns per tile; 800 = 25 * 32 */
#define NT 25             /* tiles per block */
#define THRESH 0.7f
#define FILL (-1.0e9f)

typedef __attribute__((ext_vector_type(8))) short short8;
typedef __attribute__((ext_vector_type(16))) float f32x16;

// round-to-nearest-even float -> bf16 bits (finite inputs only)
__device__ __forceinline__ unsigned short f2bf(float x) {
  unsigned u = __builtin_bit_cast(unsigned, x);
  return (unsigned short)((u + 0x7fffu + ((u >> 16) & 1u)) >> 16);
}

// async global->LDS: 16 bytes per lane; lane i lands at ldsbase + i*16
__device__ __forceinline__ void stage16(const void* g, void* l) {
  __builtin_amdgcn_global_load_lds(
      (const __attribute__((address_space(1))) unsigned int*)g,
      (__attribute__((address_space(3))) unsigned int*)l,
      16, 0, 0);
}

// ---------------- Threefry-2x32 (JAX-compatible) ----------------
__device__ __forceinline__ void tf2x32(unsigned k0, unsigned k1,
                                       unsigned x0, unsigned x1,
                                       unsigned* o0, unsigned* o1) {
  unsigned ks2 = k0 ^ k1 ^ 0x1BD11BDAu;
  unsigned v0 = x0 + k0, v1 = x1 + k1;
#define TFR(r) { v0 += v1; v1 = (v1 << r) | (v1 >> (32 - r)); v1 ^= v0; }
  TFR(13) TFR(15) TFR(26) TFR(6)   v0 += k1;  v1 += ks2 + 1u;
  TFR(17) TFR(29) TFR(16) TFR(24)  v0 += ks2; v1 += k0 + 2u;
  TFR(13) TFR(15) TFR(26) TFR(6)   v0 += k0;  v1 += k1 + 3u;
  TFR(17) TFR(29) TFR(16) TFR(24)  v0 += k1;  v1 += ks2 + 4u;
  TFR(13) TFR(15) TFR(26) TFR(6)   v0 += ks2; v1 += k0 + 5u;
#undef TFR
  *o0 = v0; *o1 = v1;
}

__device__ __forceinline__ unsigned rbits32(unsigned ka, unsigned kb, unsigned m) {
  unsigned o0, o1;
  tf2x32(ka, kb, 0u, m, &o0, &o1);
  return o0 ^ o1;
}

// ---- kernel 1: normalize src rows -> bf16 A-fragments (fragment-major), zero counters
// Fragment layout: chunk ((ms*8 + ks)*64 + lane64) is 8 bf16 (16 B) holding
// A[row = ms*32 + (lane64&31)][col = ks*16 + (lane64>>5)*8 + t], t=0..7.
__global__ void prep_kernel(const float* __restrict__ memory,
                            const int* __restrict__ src_nodes,
                            unsigned short* __restrict__ s16f,
                            int* __restrict__ cand_cnt) {
  int tid = threadIdx.x;
  int gid = blockIdx.x * 256 + tid;
  if (gid < BATCH) cand_cnt[gid] = 0;
  int row = blockIdx.x * 4 + (tid >> 6);   // 256 blocks x 4 waves = 1024 rows
  int L = tid & 63;                        // lane within the row's wave; cols 2L,2L+1
  int s = src_nodes[row];
  float2 v = ((const float2*)(memory + (size_t)s * DIM))[L];
  float ss = v.x * v.x + v.y * v.y;
#pragma unroll
  for (int off = 32; off > 0; off >>= 1) ss += __shfl_xor(ss, off);
  float inv = 1.0f / fmaxf(sqrtf(ss), 1e-12f);
  unsigned p = (unsigned)f2bf(v.x * inv) | ((unsigned)f2bf(v.y * inv) << 16);
  int ms = row >> 5, l32 = row & 31;
  int c = L >> 2;             // col chunk = col/8
  int ks = c >> 1, half = c & 1;
  ((unsigned*)s16f)[(((ms * 8 + ks) * 64) + half * 32 + l32) * 4 + (L & 3)] = p;
}

// ---- kernel 2: R13 dataflow + distance-2 prefetch with counted vmcnt ----
// Identical to the verified 65-us R13 kernel (per-wave global_load_lds
// staging of own 4 cols, convert-once into XOR-swizzled frag LDS, one
// barrier/tile, scale-after-MFMA) with ONE change: the DMA for tile t+2 is
// issued at iter t into a 2-slot wave-private qbuf, and the convert of tile
// t+1 waits `vmcnt(2)` — the 2 newest outstanding ops (tile t+2's DMAs) may
// remain in flight, so each DMA gets a FULL iteration (~6000 cyc) to land
// instead of one MFMA phase. Hit-path stores are newer than the needed DMAs,
// so vmcnt(2) only ever over-waits (correct). Last iterations use vmcnt(0).
__global__ __launch_bounds__(512, 2) void sim_scan_kernel(
    const float* __restrict__ memory,
    const unsigned short* __restrict__ s16f,
    const int* __restrict__ dst_nodes,
    int* __restrict__ cand_cnt,
    float* __restrict__ cand_val,
    int* __restrict__ cand_idx) {
  __shared__ char qbuf[8][4096];             // per-wave staged raw cols (2 slots x 2 KB)
  __shared__ unsigned short fragb[2][4096];  // bf16 frags, [seg16][col32^swz] x 16 B
  __shared__ float nrmb[2][32];              // per-column L2 norms

  int tid = threadIdx.x;
  int wid = tid >> 6;
  int lane = tid & 63;
  int half = lane >> 5;
  int l32 = lane & 31;
  int jb0 = blockIdx.x * CPB;

  int ccol = wid * 4 + (lane & 3);   // this lane's owned column (0..31 in tile)
  int cseg = lane >> 2;              // element group [cseg*8, cseg*8+8)

  const char* mb = (const char*)memory;
  char* qb = &qbuf[wid][0];

  // stage tile t's own-4-columns into qbuf slot `slot` (2 DMAs)
#define QSTAGE(t, slot) {                                                       \
    const char* g = mb + (size_t)(jb0 + (t) * TCOL + ccol) * 512 + (cseg << 5); \
    stage16(g, qb + (slot) * 2048);                                             \
    stage16(g + 16, qb + (slot) * 2048 + 1024);                                 \
  }

  // read back own 32 B from qbuf slot `slot`, convert -> frag[p]/nrm[p]
  // (caller has already done the appropriate s_waitcnt)
#define QCONVERT(p, slot) {                                                     \
    float4 q0 = *(const float4*)(qb + (slot) * 2048 + (lane << 4));             \
    float4 q1 = *(const float4*)(qb + (slot) * 2048 + 1024 + (lane << 4));      \
    float ss = q0.x * q0.x + q0.y * q0.y + q0.z * q0.z + q0.w * q0.w            \
             + q1.x * q1.x + q1.y * q1.y + q1.z * q1.z + q1.w * q1.w;           \
    ss += __shfl_xor(ss, 4); ss += __shfl_xor(ss, 8);                           \
    ss += __shfl_xor(ss, 16); ss += __shfl_xor(ss, 32);                         \
    short8 f;                                                                   \
    f[0] = (short)f2bf(q0.x); f[1] = (short)f2bf(q0.y);                         \
    f[2] = (short)f2bf(q0.z); f[3] = (short)f2bf(q0.w);                         \
    f[4] = (short)f2bf(q1.x); f[5] = (short)f2bf(q1.y);                         \
    f[6] = (short)f2bf(q1.z); f[7] = (short)f2bf(q1.w);                         \
    *(short8*)((char*)fragb[p] + ((cseg * 32 + (ccol ^ (cseg & 7))) << 4)) = f; \
    if (cseg == 0) nrmb[p][ccol] = fmaxf(sqrtf(ss), 1e-12f);                    \
  }

  // ---- prologue: stage tiles 0,1 (slots 0,1), A-load, convert t0, barrier ----
  QSTAGE(0, 0);
  QSTAGE(1, 1);
  const short8* __restrict__ af = (const short8*)s16f;
  short8 a[4][8];
#pragma unroll
  for (int m = 0; m < 4; ++m)
#pragma unroll
    for (int ks = 0; ks < 8; ++ks)
      a[m][ks] = af[(((wid * 4 + m) * 8) + ks) * 64 + lane];
  asm volatile("s_waitcnt vmcnt(0)" ::: "memory");
  __builtin_amdgcn_sched_barrier(0);
  QCONVERT(0, 0);
  __syncthreads();          // frag[0] visible

  f32x16 Z;
#pragma unroll
  for (int i = 0; i < 16; ++i) Z[i] = 0.0f;

  // ---- main loop: one barrier per tile; distance-2 DMA pipeline ----
  for (int t = 0; t < NT; ++t) {
    int par = t & 1;

    // (a) issue tile t+2's DMA into slot (t&1)  [(t+2)&1 == t&1; that slot's
    //     tile t was converted at iter t-1 -> free]
    if (t + 2 < NT) QSTAGE(t + 2, par);

    // (b) MFMA phase on frag[par]  (R13 body, unchanged)
    float nv = nrmb[par][l32];
    float thr = THRESH * nv;
    float invv = 1.0f / nv;
    int gj = jb0 + t * TCOL + l32;
    short8 bf[8];
#pragma unroll
    for (int ks = 0; ks < 8; ++ks) {
      int s0 = 2 * ks + half;
      bf[ks] = *(const short8*)((char*)fragb[par] + ((s0 * 32 + (l32 ^ (s0 & 7))) << 4));
    }

#pragma unroll
    for (int mp = 0; mp < 2; ++mp) {
      f32x16 accA = __builtin_amdgcn_mfma_f32_32x32x16_bf16(a[mp * 2][0], bf[0], Z, 0, 0, 0);
      f32x16 accB = __builtin_amdgcn_mfma_f32_32x32x16_bf16(a[mp * 2 + 1][0], bf[0], Z, 0, 0, 0);
#pragma unroll
      for (int ks = 1; ks < 8; ++ks) {
        accA = __builtin_amdgcn_mfma_f32_32x32x16_bf16(a[mp * 2][ks], bf[ks], accA, 0, 0, 0);
        accB = __builtin_amdgcn_mfma_f32_32x32x16_bf16(a[mp * 2 + 1][ks], bf[ks], accB, 0, 0, 0);
      }
      float mA = accA[0], mB = accB[0];
#pragma unroll
      for (int i2 = 1; i2 < 16; ++i2) { mA = fmaxf(mA, accA[i2]); mB = fmaxf(mB, accB[i2]); }
      if (mA > thr || mB > thr) {
        // C/D layout (m74/m101): col=lane&31, row=(r&3)+8*(r>>2)+4*(lane>>5)
#pragma unroll
        for (int e = 0; e < 2; ++e) {
#pragma unroll
          for (int r = 0; r < 16; ++r) {
            float raw = (e == 0) ? accA[r] : accB[r];
            if (raw > thr) {
              int gi = (wid * 4 + mp * 2 + e) * 32 + (r & 3) + 8 * (r >> 2) + 4 * half;
              if (gj != dst_nodes[gi]) {
                int pq = atomicAdd(&cand_cnt[gi], 1);
                if (pq < CAP) {
                  cand_val[gi * CAP + pq] = raw * invv;
                  cand_idx[gi * CAP + pq] = gj;
                }
              }
            }
          }
        }
      }
    }

    // (c) counted wait + convert tile t+1 from slot ((t+1)&1) -> frag[par^1]
    if (t + 1 < NT) {
      if (t + 2 < NT) {
        // tile t+2's 2 DMAs (newest) may stay in flight; tile t+1's are done.
        // Any hit-path stores are newer than t+1's DMAs -> only over-waits.
        asm volatile("s_waitcnt vmcnt(2)" ::: "memory");
      } else {
        asm volatile("s_waitcnt vmcnt(0)" ::: "memory");
      }
      __builtin_amdgcn_sched_barrier(0);
      QCONVERT(par ^ 1, (t + 1) & 1);
    }

    // (d) barrier: frag[par^1] visible; frag[par] free at t+2
    __syncthreads();
  }
#undef QSTAGE
#undef QCONVERT
}

// ---- kernel 3: top-5 per row, threefry negatives, assemble ----
__global__ void finalize_kernel(const int* __restrict__ src_nodes,
                                const int* __restrict__ dst_nodes,
                                const float* __restrict__ labels,
                                const float* __restrict__ ts,
                                const int* __restrict__ cand_cnt,
                                const float* __restrict__ cand_val,
                                const int* __restrict__ cand_idx,
                                float* __restrict__ out) {
  int r = blockIdx.x * 256 + threadIdx.x;
  if (r >= BATCH) return;
  const int TOT = BATCH + BATCH * K_NEG;  // 6144
  int srcv = src_nodes[r];
  float tsv = ts[r];
  out[r] = (float)srcv;
  out[TOT + r] = (float)dst_nodes[r];
  float l = labels[r];
  out[2 * TOT + r] = l * 0.9f + (1.0f - l) * 0.1f;
  out[3 * TOT + r] = tsv;

  int cnt = cand_cnt[r];
  cnt = cnt < CAP ? cnt : CAP;
  float cv[CAP]; int ci[CAP];
  for (int i = 0; i < cnt; ++i) { cv[i] = cand_val[r * CAP + i]; ci[i] = cand_idx[r * CAP + i]; }

  // jax.random.split(key(42)) — partitionable/foldlike: k_i = threefry(key, 0, i)
  unsigned k1a, k1b, k2a, k2b;
  tf2x32(0u, 42u, 0u, 0u, &k1a, &k1b);
  tf2x32(0u, 42u, 0u, 1u, &k2a, &k2b);

  const unsigned span = 200000u;
  const unsigned mult = 167296u;  // 2^32 % span

  for (int s = 0; s < K_NEG; ++s) {
    int sel = -1;
    for (int i = 0; i < cnt; ++i)
      if (sel < 0 || cv[i] > cv[sel] || (cv[i] == cv[sel] && ci[i] < ci[sel])) sel = i;
    float v = FILL; int idx = 0;
    if (sel >= 0) { v = cv[sel]; idx = ci[sel]; cv[sel] = FILL; ci[sel] = 0x7fffffff; }
    bool is_real = v > (FILL + 1.0f);

    unsigned m = (unsigned)(r * K_NEG + s);
    unsigned hi = rbits32(k1a, k1b, m);
    unsigned lo = rbits32(k2a, k2b, m);
    unsigned off = ((hi % span) * mult + (lo % span)) % span;  // uint32 wrap, as JAX
    int rd = (int)off;
    if (rd == srcv) rd = (rd + 1) % NUM_NODES;
    int fd = is_real ? idx : rd;

    int mi = (int)m;
    out[BATCH + mi] = (float)srcv;
    out[TOT + BATCH + mi] = (float)fd;
    out[2 * TOT + BATCH + mi] = 0.1f;   // smoothing of label 0
    out[3 * TOT + BATCH + mi] = tsv;
    out[4 * TOT + mi] = v;
  }
}

extern "C" void kernel_launch(void* const* d_in, const int* in_sizes, int n_in,
                              void* d_out, int out_size, void* d_ws, size_t ws_size,
                              hipStream_t stream) {
  const int* src = (const int*)d_in[0];
  const int* dst = (const int*)d_in[1];
  const float* labels = (const float*)d_in[2];
  const float* ts = (const float*)d_in[3];
  const float* memory = (const float*)d_in[4];
  float* out = (float*)d_out;

  char* ws = (char*)d_ws;
  unsigned short* s16f = (unsigned short*)ws;       // 1024*128*2 = 262144 B (fragment-major)
  int* cand_cnt = (int*)(ws + 262144);              // 4096 B
  float* cand_val = (float*)(ws + 266240);          // 65536 B
  int* cand_idx = (int*)(ws + 331776);              // 65536 B

  prep_kernel<<<256, 256, 0, stream>>>(memory, src, s16f, cand_cnt);
  sim_scan_kernel<<<NBLK, 512, 0, stream>>>(memory, s16f, dst, cand_cnt, cand_val, cand_idx);
  finalize_kernel<<<(BATCH + 255) / 256, 256, 0, stream>>>(src, dst, labels, ts,
                                                           cand_cnt, cand_val, cand_idx, out);
}